// Round 5
// baseline (1263.143 us; speedup 1.0000x reference)
//
#include <hip/hip_runtime.h>
#include <stdint.h>
#include <math.h>

#define HW    524288      // 512*1024 pixels
#define NETA  7
#define F     68          // NPROG*LEV
#define OC    17          // outputs per thread (F/4)
#define GROUPS_MAX (HW / 64 + NETA)   // 8199 64-pixel expert-pure groups (worst case)

// ---------------- threefry2x32, key = (0, 42) ----------------
// partitionable path: counter=(0,i), bits = o0 ^ o1. Bit-exact (R3: absmax 0.0).
__device__ __forceinline__ uint32_t threefry_xor_k42(uint32_t x0, uint32_t x1) {
  const uint32_t ks0 = 0u;
  const uint32_t ks1 = 42u;
  const uint32_t ks2 = 0x1BD11BDAu ^ ks0 ^ ks1;
  x0 += ks0; x1 += ks1;
#define RND(r) { x0 += x1; x1 = (x1 << (r)) | (x1 >> (32 - (r))); x1 ^= x0; }
  RND(13) RND(15) RND(26) RND(6)   x0 += ks1; x1 += ks2 + 1u;
  RND(17) RND(29) RND(16) RND(24)  x0 += ks2; x1 += ks0 + 2u;
  RND(13) RND(15) RND(26) RND(6)   x0 += ks0; x1 += ks1 + 3u;
  RND(17) RND(29) RND(16) RND(24)  x0 += ks1; x1 += ks2 + 4u;
  RND(13) RND(15) RND(26) RND(6)   x0 += ks2; x1 += ks0 + 5u;
#undef RND
  return x0 ^ x1;
}

// ---------------- k1: categorical sampling (exact) + expert histogram ----------------
__global__ void __launch_bounds__(256) eta_kernel(const float* __restrict__ T,
                                                  const int* __restrict__ eta,
                                                  int* __restrict__ eta_new,
                                                  int* __restrict__ hist) {
  __shared__ float  rinv32[NETA * NETA];
  __shared__ double rinv64[NETA * NETA];
  __shared__ int lh[NETA];
  const int tid = threadIdx.x;
  if (tid < NETA * NETA) {
    double d = 1.0 / ((double)T[tid] + 1e-9);
    rinv64[tid] = d;
    rinv32[tid] = (float)d;
  }
  if (tid < NETA) lh[tid] = 0;
  __syncthreads();

  const int p = blockIdx.x * 256 + tid;
  const int r = eta[p];

  // exponential race == gumbel argmax (monotone transform, tie-order preserved)
  float w[NETA];
#pragma unroll
  for (int k = 0; k < NETA; k++) {
    const uint32_t bits = threefry_xor_k42(0u, (uint32_t)(7 * p + k));
    const float f = __uint_as_float((bits >> 9) | 0x3f800000u) - 1.0f;
    const float u = (f == 0.0f) ? 1.1754943508222875e-38f : f;
    w[k] = (-__log2f(u)) * rinv32[r * NETA + k];
  }
  float w1 = w[0], w2 = 3.4e38f;
  int e = 0;
#pragma unroll
  for (int k = 1; k < NETA; k++) {
    if (w[k] < w1)      { w2 = w1; w1 = w[k]; e = k; }
    else if (w[k] < w2) { w2 = w[k]; }
  }
  if (!((w2 - w1) > 3e-5f * w2)) {           // ambiguous -> exact f64 race (rare)
    double b1 = 1e300;
    e = 0;
    for (int k = 0; k < NETA; k++) {
      const uint32_t bits = threefry_xor_k42(0u, (uint32_t)(7 * p + k));
      const float f = __uint_as_float((bits >> 9) | 0x3f800000u) - 1.0f;
      const double u = (f == 0.0f) ? (double)1.1754943508222875e-38f : (double)f;
      const double wv = -log(u) * rinv64[r * NETA + k];
      if (wv < b1) { b1 = wv; e = k; }
    }
  }
  eta_new[p] = e;

  if (hist) {
    atomicAdd(&lh[e], 1);
    __syncthreads();
    if (tid < NETA) atomicAdd(&hist[tid], lh[tid]);
  }
}

// ---------------- k2: bucket bases (padded to 64), cursors, group->expert map ----------------
__global__ void setup_kernel(const int* __restrict__ hist,
                             int* __restrict__ cursor,
                             int* __restrict__ grp_e) {
  __shared__ int bp[NETA + 1];
  if (threadIdx.x == 0) {
    int off = 0;
    for (int e = 0; e < NETA; e++) { bp[e] = off; off += ((hist[e] + 63) >> 6) << 6; }
    bp[NETA] = off;
  }
  __syncthreads();
  if (threadIdx.x < NETA) cursor[threadIdx.x] = bp[threadIdx.x];
  for (int g = threadIdx.x; g < GROUPS_MAX; g += blockDim.x) {
    const int start = g << 6;
    int e = -1;
    for (int k = 0; k < NETA; k++)
      if (start >= bp[k] && start < bp[k + 1]) e = k;
    grp_e[g] = e;
  }
}

// ---------------- k3: scatter pixel ids into expert buckets (wave-aggregated atomics) ----------------
__global__ void __launch_bounds__(256) scatter_kernel(const int* __restrict__ eta_new,
                                                      int* __restrict__ cursor,
                                                      int* __restrict__ idx) {
  const int p = blockIdx.x * 256 + threadIdx.x;
  const int e = eta_new[p];
  const int lane = threadIdx.x & 63;
#pragma unroll
  for (int k = 0; k < NETA; k++) {
    const unsigned long long m = __ballot(e == k);   // wave-uniform
    if (m == 0ull) continue;
    const int leader = __builtin_ctzll(m);
    int base = 0;
    if (lane == leader) base = atomicAdd(&cursor[k], (int)__popcll(m));
    base = __shfl(base, leader, 64);
    if (e == k) {
      const int nbelow = (int)__popcll(m & ((1ull << lane) - 1ull));
      idx[base + nbelow] = p;
    }
  }
}

// ---------------- k4: sorted expert matvec — wave-uniform W via SGPRs ----------------
// Block = one 64-pixel expert-pure group x 4 o-chunks. W/b addresses are scalar
// (e uniform per block, c forced scalar via readfirstlane) -> s_load, FMAs are
// v_fmac v,s,v. Only x-gather / out-scatter are divergent (34 VMEM/wave).
__global__ void __launch_bounds__(256, 4) expert_sorted_kernel(const float* __restrict__ x,
                                                               const float* __restrict__ W,
                                                               const float* __restrict__ b,
                                                               const int* __restrict__ idx,
                                                               const int* __restrict__ grp_e,
                                                               float* __restrict__ out) {
  __shared__ float xs[F][64];
  const int tid = threadIdx.x;
  const int pl  = tid & 63;
  const int c0  = tid >> 6;
  const int g   = blockIdx.x;
  const int e   = grp_e[g];                     // block-uniform (scalar)
  if (e < 0) return;                            // unused trailing group (uniform exit)
  const int c = __builtin_amdgcn_readfirstlane(c0);

  const int p  = idx[(g << 6) + pl];            // may be -1 (bucket pad)
  const int ps = (p < 0) ? 0 : p;

  // stage this group's x columns (divergent gather, 17 insts/thread)
#pragma unroll
  for (int i = 0; i < 17; i++) {
    const int f = c0 + 4 * i;
    xs[f][pl] = x[(size_t)f * HW + ps];
  }
  __syncthreads();

  const float* __restrict__ Wp = W + (size_t)e * (F * F) + (size_t)(c * OC) * F;

  float acc[OC];
#pragma unroll
  for (int o = 0; o < OC; o++) acc[o] = 0.0f;

#pragma unroll 1
  for (int f4 = 0; f4 < F / 4; f4++) {
    const float xv0 = xs[4 * f4 + 0][pl];
    const float xv1 = xs[4 * f4 + 1][pl];
    const float xv2 = xs[4 * f4 + 2][pl];
    const float xv3 = xs[4 * f4 + 3][pl];
#pragma unroll
    for (int o = 0; o < OC; o++) {
      const float* wr = Wp + o * F + 4 * f4;    // scalar address -> s_load
      float a = acc[o];
      a = fmaf(wr[0], xv0, a);                  // same FMA order as R4 (absmax 0.0)
      a = fmaf(wr[1], xv1, a);
      a = fmaf(wr[2], xv2, a);
      a = fmaf(wr[3], xv3, a);
      acc[o] = a;
    }
  }

  if (p >= 0) {
    const float* __restrict__ bp = b + e * F + c * OC;
#pragma unroll
    for (int o = 0; o < OC; o++)
      out[(size_t)(c * OC + o) * HW + p] = acc[o] + bp[o];
  }
}

// ---------------- fallback (R4 path) if workspace is too small ----------------
__global__ void __launch_bounds__(256, 4) expert_kernel(const float* __restrict__ x,
                                                        const float* __restrict__ W,
                                                        const float* __restrict__ b,
                                                        const int* __restrict__ eta_new,
                                                        float* __restrict__ out) {
  __shared__ float xs[F][64];
  const int tid = threadIdx.x;
  const int pl  = tid & 63;
  const int c   = tid >> 6;
  const int p   = blockIdx.x * 64 + pl;
  const int e   = eta_new[p];
#pragma unroll
  for (int i = 0; i < 17; i++) {
    const int f = c + 4 * i;
    xs[f][pl] = x[(size_t)f * HW + p];
  }
  __syncthreads();
  const float* __restrict__ Wp = W + (size_t)e * (F * F) + (size_t)(c * OC) * F;
  float acc[OC];
#pragma unroll
  for (int o = 0; o < OC; o++) acc[o] = 0.0f;
#pragma unroll 1
  for (int f4 = 0; f4 < F / 4; f4++) {
    const float xv0 = xs[4 * f4 + 0][pl];
    const float xv1 = xs[4 * f4 + 1][pl];
    const float xv2 = xs[4 * f4 + 2][pl];
    const float xv3 = xs[4 * f4 + 3][pl];
#pragma unroll
    for (int o = 0; o < OC; o++) {
      const float4 w = *reinterpret_cast<const float4*>(Wp + o * F + 4 * f4);
      float a = acc[o];
      a = fmaf(w.x, xv0, a);
      a = fmaf(w.y, xv1, a);
      a = fmaf(w.z, xv2, a);
      a = fmaf(w.w, xv3, a);
      acc[o] = a;
    }
  }
  const float* __restrict__ bp = b + e * F + c * OC;
#pragma unroll
  for (int o = 0; o < OC; o++)
    out[(size_t)(c * OC + o) * HW + p] = acc[o] + bp[o];
}

extern "C" void kernel_launch(void* const* d_in, const int* in_sizes, int n_in,
                              void* d_out, int out_size, void* d_ws, size_t ws_size,
                              hipStream_t stream) {
  const float* x   = (const float*)d_in[0];
  const float* W   = (const float*)d_in[1];
  const float* b   = (const float*)d_in[2];
  const float* T   = (const float*)d_in[3];
  const int*   eta = (const int*)d_in[4];
  float* out = (float*)d_out;

  // ws layout: etabuf[HW] | idx[HW+448] | hist[8] | cursor[8] | grp_e[GROUPS_MAX]
  const size_t off_eta    = 0;
  const size_t off_idx    = off_eta + (size_t)HW * 4;
  const size_t off_hist   = off_idx + (size_t)(HW + NETA * 64) * 4;
  const size_t off_cursor = off_hist + 8 * 4;
  const size_t off_grpe   = off_cursor + 8 * 4;
  const size_t ws_needed  = off_grpe + (size_t)GROUPS_MAX * 4;

  if (ws_size >= ws_needed) {
    char* wsb = (char*)d_ws;
    int* etabuf = (int*)(wsb + off_eta);
    int* idx    = (int*)(wsb + off_idx);
    int* hist   = (int*)(wsb + off_hist);
    int* cursor = (int*)(wsb + off_cursor);
    int* grp_e  = (int*)(wsb + off_grpe);

    hipMemsetAsync(hist, 0, 8 * 4, stream);
    hipMemsetAsync(idx, 0xFF, (size_t)(HW + NETA * 64) * 4, stream);  // sentinel -1
    eta_kernel<<<HW / 256, 256, 0, stream>>>(T, eta, etabuf, hist);
    setup_kernel<<<1, 256, 0, stream>>>(hist, cursor, grp_e);
    scatter_kernel<<<HW / 256, 256, 0, stream>>>(etabuf, cursor, idx);
    expert_sorted_kernel<<<GROUPS_MAX, 256, 0, stream>>>(x, W, b, idx, grp_e, out);
  } else {
    // fallback: R4 path, eta in out row 67 (read-before-write within each block)
    int* etabuf = (ws_size >= sizeof(int) * (size_t)HW)
                      ? (int*)d_ws
                      : ((int*)d_out) + (size_t)(F - 1) * HW;
    eta_kernel<<<HW / 256, 256, 0, stream>>>(T, eta, etabuf, (int*)nullptr);
    expert_kernel<<<HW / 64, 256, 0, stream>>>(x, W, b, etabuf, out);
  }
}